// Round 11
// baseline (176.670 us; speedup 1.0000x reference)
//
#include <hip/hip_runtime.h>
#include <hip/hip_bf16.h>
#include <math.h>
#include <stdint.h>

// Problem constants
#define S_LEN  2048
#define HID    1024
#define NHEADS 16
#define NE     256
#define NMEN   1024
#define NP     2048
#define PHID   1024

typedef __attribute__((ext_vector_type(8))) short bf16x8;
typedef __attribute__((ext_vector_type(4))) float f32x4;
typedef unsigned int uint;

// ---------------------------------------------------------------------------
// Helpers
// ---------------------------------------------------------------------------
__device__ inline void seg_bounds(const int* __restrict__ entity_ids, int e,
                                  int& start, int& end) {
    int lo = 0, hi = NMEN;
    while (lo < hi) { int mid = (lo + hi) >> 1; if (entity_ids[mid] < e) lo = mid + 1; else hi = mid; }
    start = lo;
    hi = NMEN;
    while (lo < hi) { int mid = (lo + hi) >> 1; if (entity_ids[mid] <= e) lo = mid + 1; else hi = mid; }
    end = lo;
}

__device__ __forceinline__ void load_lds16(const void* g, void* l) {
    __builtin_amdgcn_global_load_lds(
        (const __attribute__((address_space(1))) uint32_t*)g,
        (__attribute__((address_space(3))) uint32_t*)l,
        16, 0, 0);
}

__device__ __forceinline__ float bflo(uint u) { return __uint_as_float(u << 16); }
__device__ __forceinline__ float bfhi(uint u) { return __uint_as_float(u & 0xffff0000u); }
__device__ __forceinline__ uint pk2(float a, float b) {
    __hip_bfloat16 ha = __float2bfloat16(a), hb = __float2bfloat16(b);
    unsigned short ua = *(unsigned short*)&ha, ub = *(unsigned short*)&hb;
    return (uint)ua | ((uint)ub << 16);
}

// ---------------------------------------------------------------------------
// L1) Merged prep + entity kernel (round-9 structure, LOW LDS), 8960 blocks:
//   [0,1024)      seq fp32 -> bf16 cast (row-major)
//   [1024,4096)   3 weight transposes (W_ctx, W_head, W_tail) -> bf16
//   [4096,4608)   W_bil fp32 -> bf16 cast (row-major)
//   [4608,8960)   entity: e = t&255, role = t>>8 (0..15: att head; 16: emb)
// ---------------------------------------------------------------------------
__global__ void prep_ent_kernel(const float* __restrict__ seq,
                                const float* __restrict__ attention,
                                const float* __restrict__ w0, const float* __restrict__ w1,
                                const float* __restrict__ w2, const float* __restrict__ wbil,
                                const int* __restrict__ mention_idx,
                                const int* __restrict__ entity_ids,
                                __hip_bfloat16* __restrict__ seqB,
                                __hip_bfloat16* __restrict__ o0, __hip_bfloat16* __restrict__ o1,
                                __hip_bfloat16* __restrict__ o2, __hip_bfloat16* __restrict__ obil,
                                uint2* __restrict__ eaB,
                                __hip_bfloat16* __restrict__ ent_emb)
{
    __shared__ float tbuf[32][33];
    __shared__ int sb[2];
    int id = blockIdx.x;
    if (id < 1024) {
        long i = (long)id * 256 + threadIdx.x;
        const float4* in4 = (const float4*)seq;
        float4 a = in4[2 * i], b = in4[2 * i + 1];
        uint4 o;
        o.x = pk2(a.x, a.y); o.y = pk2(a.z, a.w);
        o.z = pk2(b.x, b.y); o.w = pk2(b.z, b.w);
        ((uint4*)seqB)[i] = o;
        return;
    }
    if (id < 4096) {
        int t = id - 1024;
        int z = t >> 10;
        const float* in = (z == 0) ? w0 : (z == 1) ? w1 : w2;
        __hip_bfloat16* out = (z == 0) ? o0 : (z == 1) ? o1 : o2;
        int r0 = ((t >> 5) & 31) * 32, c0 = (t & 31) * 32;
        int j = threadIdx.x & 31, i0 = threadIdx.x >> 5;
        for (int i = i0; i < 32; i += 8)
            tbuf[i][j] = in[(long)(r0 + i) * 1024 + c0 + j];
        __syncthreads();
        for (int i = i0; i < 32; i += 8)
            out[(long)(c0 + i) * 1024 + r0 + j] = __float2bfloat16(tbuf[j][i]);
        return;
    }
    if (id < 4608) {
        long i = (long)(id - 4096) * 256 + threadIdx.x;
        const float4* in4 = (const float4*)wbil;
        float4 a = in4[2 * i], b = in4[2 * i + 1];
        uint4 o;
        o.x = pk2(a.x, a.y); o.y = pk2(a.z, a.w);
        o.z = pk2(b.x, b.y); o.w = pk2(b.z, b.w);
        ((uint4*)obil)[i] = o;
        return;
    }
    // entity work
    int t = id - 4608;
    int e = t & 255, role = t >> 8;
    if (threadIdx.x == 0) { int s, tt; seg_bounds(entity_ids, e, s, tt); sb[0] = s; sb[1] = tt; }
    __syncthreads();
    int start = sb[0], end = sb[1];

    if (role < 16) {
        const float4* att4 = (const float4*)attention;
        int h = role;
        float inv = 1.f / fmaxf((float)(end - start), 1.f);
        for (int s4 = threadIdx.x; s4 < S_LEN / 4; s4 += 256) {
            float ax = 0.f, ay = 0.f, az = 0.f, aw = 0.f;
            for (int i = start; i < end; ++i) {
                float4 v = att4[((long)h * S_LEN + mention_idx[i]) * (S_LEN / 4) + s4];
                ax += v.x; ay += v.y; az += v.z; aw += v.w;
            }
            uint2 o; o.x = pk2(ax * inv, ay * inv); o.y = pk2(az * inv, aw * inv);
            eaB[((long)e * NHEADS + h) * (S_LEN / 4) + s4] = o;
        }
    } else {
        const float4* seq4 = (const float4*)seq;
        int col4 = threadIdx.x;
        uint2 o;
        if (end <= start) {
            o.x = 0; o.y = 0;
            ((uint2*)ent_emb)[(long)e * 256 + col4] = o;
            return;
        }
        float mx = -INFINITY, my = -INFINITY, mz = -INFINITY, mw = -INFINITY;
        for (int i = start; i < end; ++i) {
            float4 v = seq4[(long)mention_idx[i] * 256 + col4];
            mx = fmaxf(mx, v.x); my = fmaxf(my, v.y); mz = fmaxf(mz, v.z); mw = fmaxf(mw, v.w);
        }
        float sx = 0.f, sy = 0.f, sz = 0.f, sw = 0.f;
        for (int i = start; i < end; ++i) {
            float4 v = seq4[(long)mention_idx[i] * 256 + col4];
            sx += expf(v.x - mx); sy += expf(v.y - my); sz += expf(v.z - mz); sw += expf(v.w - mw);
        }
        o.x = pk2(mx + logf(sx), my + logf(sy));
        o.y = pk2(mz + logf(sz), mw + logf(sw));
        ((uint2*)ent_emb)[(long)e * 256 + col4] = o;
    }
}

// ---------------------------------------------------------------------------
// Shared GEMM epilogue: 128x128 tile, 4 waves (2x2).
//    MODE 0: fp32 at slice bz (bz=0 => direct fp32)
//    MODE 1: bf16 direct
//    MODE 2: fused bilinear: atomicAdd(out+row, sum_col acc*bf16(zvec)[row][col])
// ---------------------------------------------------------------------------
template <int MODE>
__device__ __forceinline__ void gemm_epilogue(
    f32x4 (&acc)[4][4], void* __restrict__ Cout,
    const __hip_bfloat16* __restrict__ zvec, float* __restrict__ out,
    int M, int N, int bm, int bn, int bz, int wr, int wc, int lane)
{
    int lr = lane & 15;
    int q4 = (lane >> 4) * 4;
    if (MODE == 0) {
#pragma unroll
        for (int fm = 0; fm < 4; ++fm)
#pragma unroll
            for (int fn = 0; fn < 4; ++fn) {
                int row = bm + wr * 64 + fm * 16 + q4;
                int col = bn + wc * 64 + fn * 16 + lr;
#pragma unroll
                for (int r = 0; r < 4; ++r)
                    ((float*)Cout)[((long)bz * M + row + r) * N + col] = acc[fm][fn][r];
            }
    } else if (MODE == 1) {
#pragma unroll
        for (int fm = 0; fm < 4; ++fm)
#pragma unroll
            for (int fn = 0; fn < 4; ++fn) {
                int row = bm + wr * 64 + fm * 16 + q4;
                int col = bn + wc * 64 + fn * 16 + lr;
#pragma unroll
                for (int r = 0; r < 4; ++r)
                    ((__hip_bfloat16*)Cout)[(long)(row + r) * N + col] = __float2bfloat16(acc[fm][fn][r]);
            }
    } else {
#pragma unroll
        for (int fm = 0; fm < 4; ++fm) {
#pragma unroll
            for (int r = 0; r < 4; ++r) {
                int row = bm + wr * 64 + fm * 16 + q4 + r;
                float v = 0.f;
#pragma unroll
                for (int fn = 0; fn < 4; ++fn) {
                    int col = bn + wc * 64 + fn * 16 + lr;
                    v += acc[fm][fn][r] * __bfloat162float(zvec[(long)row * N + col]);
                }
                v += __shfl_xor(v, 1, 64);
                v += __shfl_xor(v, 2, 64);
                v += __shfl_xor(v, 4, 64);
                v += __shfl_xor(v, 8, 64);
                if (lr == 0) atomicAdd(out + row, v);
            }
        }
    }
}

#define COMPUTE_TILE(AsB, BsB) { _Pragma("unroll") \
    for (int sub = 0; sub < 2; ++sub) { \
        bf16x8 af[4], bfr[4]; \
        _Pragma("unroll") for (int f = 0; f < 4; ++f) { \
            af[f]  = *(const bf16x8*)&AsB[sub * 4 + kg][wr * 64 + f * 16 + lr][0]; \
            bfr[f] = *(const bf16x8*)&BsB[sub * 4 + kg][wc * 64 + f * 16 + lr][0]; \
        } \
        _Pragma("unroll") for (int fm = 0; fm < 4; ++fm) \
        _Pragma("unroll") for (int fn = 0; fn < 4; ++fn) \
            acc[fm][fn] = __builtin_amdgcn_mfma_f32_16x16x32_bf16(af[fm], bfr[fn], acc[fm][fn], 0, 0, 0); \
    } }

// ---------------------------------------------------------------------------
// Single-buffer GEMM core (32 KB LDS)
// ---------------------------------------------------------------------------
template <int MODE>
__device__ __forceinline__ void gemm_core(
    const __hip_bfloat16* __restrict__ A,
    const __hip_bfloat16* __restrict__ Bt,
    void* __restrict__ Cout, const __hip_bfloat16* __restrict__ zvec, float* __restrict__ out,
    int M, int N, int Kstride, int kLen,
    int bx, int by, int bz,
    short (*As)[128][8], short (*Bs)[128][8])
{
    int tid = threadIdx.x;
    int lane = tid & 63, wid = tid >> 6;
    int wr = wid >> 1, wc = wid & 1;
    int bm = by * 128, bn = bx * 128;
    int kBeg = bz * kLen;

    const __hip_bfloat16* gsrc[8];
    void* ldst[8];
#pragma unroll
    for (int i = 0; i < 8; ++i) {
        int c = wid * 8 + i;
        int isA = (c < 16) ? 1 : 0;
        int cc = isA ? c : c - 16;
        int kg2 = cc >> 1, rh = cc & 1;
        gsrc[i] = (isA ? A + (long)(bm + rh * 64 + lane) * Kstride
                       : Bt + (long)(bn + rh * 64 + lane) * Kstride) + kBeg + kg2 * 8;
        ldst[i] = isA ? (void*)&As[kg2][rh * 64][0] : (void*)&Bs[kg2][rh * 64][0];
    }

    f32x4 acc[4][4] = {};
    int kg = lane >> 4, lr = lane & 15;

    for (int k0 = 0; k0 < kLen; k0 += 64) {
#pragma unroll
        for (int i = 0; i < 8; ++i)
            load_lds16(gsrc[i] + k0, ldst[i]);
        __syncthreads();
        COMPUTE_TILE(As, Bs);
        __syncthreads();
    }
    gemm_epilogue<MODE>(acc, Cout, zvec, out, M, N, bm, bn, bz, wr, wc, lane);
}

// ---------------------------------------------------------------------------
// Double-buffered prefetch GEMM main loop (64 KB LDS). kLen % 128 == 0.
// Leaves result in acc; epilogue is caller's.
// ---------------------------------------------------------------------------
#define GEMM_DB_LOOP(A, Bt, Kstride, kLen, bm, bn, kBeg)                       \
    const __hip_bfloat16* gsrc[8];                                             \
    void *ld0[8], *ld1[8];                                                     \
    _Pragma("unroll")                                                          \
    for (int i = 0; i < 8; ++i) {                                              \
        int c = wid * 8 + i;                                                   \
        int isA = (c < 16) ? 1 : 0;                                            \
        int cc = isA ? c : c - 16;                                             \
        int kg2 = cc >> 1, rh = cc & 1;                                        \
        gsrc[i] = (isA ? (A) + (long)((bm) + rh * 64 + lane) * (Kstride)       \
                       : (Bt) + (long)((bn) + rh * 64 + lane) * (Kstride))     \
                  + (kBeg) + kg2 * 8;                                          \
        ld0[i] = isA ? (void*)&As[0][kg2][rh * 64][0] : (void*)&Bs[0][kg2][rh * 64][0]; \
        ld1[i] = isA ? (void*)&As[1][kg2][rh * 64][0] : (void*)&Bs[1][kg2][rh * 64][0]; \
    }                                                                          \
    int nSteps = (kLen) >> 6;                                                  \
    { _Pragma("unroll") for (int i = 0; i < 8; ++i) load_lds16(gsrc[i], ld0[i]); } \
    __syncthreads();                                                           \
    for (int step = 0; step < nSteps; step += 2) {                             \
        { _Pragma("unroll") for (int i = 0; i < 8; ++i)                        \
            load_lds16(gsrc[i] + (step + 1) * 64, ld1[i]); }                   \
        COMPUTE_TILE(As[0], Bs[0]);                                            \
        __syncthreads();                                                       \
        if (step + 2 < nSteps) {                                               \
            _Pragma("unroll") for (int i = 0; i < 8; ++i)                      \
                load_lds16(gsrc[i] + (step + 2) * 64, ld0[i]);                 \
        }                                                                      \
        COMPUTE_TILE(As[1], Bs[1]);                                            \
        __syncthreads();                                                       \
    }

// ---------------------------------------------------------------------------
// L2) Merged: seqW GEMM (128 blocks, MODE 1) + ehet GEMM (32 blocks, full-K,
//     fp32 direct) + pair attention (2048 blocks). Grid 2208.
// ---------------------------------------------------------------------------
__launch_bounds__(256)
__global__ void pair_seqw_ehet(const __hip_bfloat16* __restrict__ WctxT,
                               const __hip_bfloat16* __restrict__ seqB,
                               __hip_bfloat16* __restrict__ seqWT,
                               const __hip_bfloat16* __restrict__ embB,
                               const __hip_bfloat16* __restrict__ WhtT,
                               float* __restrict__ ehet,
                               const uint4* __restrict__ ea,
                               const int* __restrict__ pair_h,
                               const int* __restrict__ pair_t,
                               uint4* __restrict__ patt)
{
    __shared__ short As[8][128][8];
    __shared__ short Bs[8][128][8];
    int id = blockIdx.x;
    if (id < 128) {
        // seqWT[j][s] = (seq@W_ctx)[s][j]: A=WctxT, Bt=seqB; M=1024,N=2048,K=1024
        gemm_core<1>(WctxT, seqB, seqWT, nullptr, nullptr,
                     PHID, S_LEN, HID, HID, id & 15, id >> 4, 0, As, Bs);
        return;
    }
    if (id < 160) {
        // ehet = ent_emb @ [W_head|W_tail]: M=256,N=2048,K=1024 full-K, fp32 direct
        int u = id - 128;
        gemm_core<0>(embB, WhtT, ehet, nullptr, nullptr,
                     NE, 2 * PHID, HID, HID, u & 15, u >> 4, 0, As, Bs);
        return;
    }
    // pair attention
    __shared__ float wsum[4];
    int p = id - 160;
    long bh = (long)pair_h[p] * NHEADS * (S_LEN / 8);
    long bt = (long)pair_t[p] * NHEADS * (S_LEN / 8);
    int s8 = threadIdx.x;
    float a0 = 0, a1 = 0, a2 = 0, a3 = 0, a4 = 0, a5 = 0, a6 = 0, a7 = 0;
#pragma unroll
    for (int h = 0; h < NHEADS; ++h) {
        uint4 xa = ea[bh + h * (S_LEN / 8) + s8];
        uint4 xb = ea[bt + h * (S_LEN / 8) + s8];
        a0 += bflo(xa.x) * bflo(xb.x); a1 += bfhi(xa.x) * bfhi(xb.x);
        a2 += bflo(xa.y) * bflo(xb.y); a3 += bfhi(xa.y) * bfhi(xb.y);
        a4 += bflo(xa.z) * bflo(xb.z); a5 += bfhi(xa.z) * bfhi(xb.z);
        a6 += bflo(xa.w) * bflo(xb.w); a7 += bfhi(xa.w) * bfhi(xb.w);
    }
    float psum = a0 + a1 + a2 + a3 + a4 + a5 + a6 + a7;
#pragma unroll
    for (int off = 32; off > 0; off >>= 1)
        psum += __shfl_down(psum, off, 64);
    int lane = threadIdx.x & 63, wid = threadIdx.x >> 6;
    if (lane == 0) wsum[wid] = psum;
    __syncthreads();
    float inv = 1.f / (wsum[0] + wsum[1] + wsum[2] + wsum[3] + 1e-6f);
    uint4 o;
    o.x = pk2(a0 * inv, a1 * inv); o.y = pk2(a2 * inv, a3 * inv);
    o.z = pk2(a4 * inv, a5 * inv); o.w = pk2(a6 * inv, a7 * inv);
    patt[(long)p * (S_LEN / 8) + s8] = o;
}

// ---------------------------------------------------------------------------
// L3) Fused ctxp + zs/zo: C = pattB @ seqWT^T (M=2048,N=1024,K=2048 full),
//     epilogue: zs=tanh(ehet[ph][j]+b_head[j]+C), zo=tanh(ehet[pt][1024+j]+b_tail[j]+C)
//     128 blocks (8 col-tiles x 16 row-tiles), dbuf, XCD-chunked.
//     Blocks with bn==0 also init out[row] = b_bil.
// ---------------------------------------------------------------------------
__launch_bounds__(256)
__global__ void gemm_fused_zszo(const __hip_bfloat16* __restrict__ pattB,
                                const __hip_bfloat16* __restrict__ seqWT,
                                const float* __restrict__ ehet,     // [E][2PH] fp32
                                const float* __restrict__ b_head,
                                const float* __restrict__ b_tail,
                                const int* __restrict__ pair_h,
                                const int* __restrict__ pair_t,
                                __hip_bfloat16* __restrict__ zs,
                                __hip_bfloat16* __restrict__ zo,
                                const float* __restrict__ b_bil,
                                float* __restrict__ out)
{
    __shared__ short As[2][8][128][8];
    __shared__ short Bs[2][8][128][8];
    int id = blockIdx.x;
    // XCD-chunked bijection over 128 = 8 XCD-groups x 16: same bx per group
    int f = (id & 7) * 16 + (id >> 3);
    int bx = f >> 4, by = f & 15;

    int tid = threadIdx.x;
    int lane = tid & 63, wid = tid >> 6;
    int wr = wid >> 1, wc = wid & 1;
    int bm = by * 128, bn = bx * 128;
    f32x4 acc[4][4] = {};
    int kg = lane >> 4, lr = lane & 15;

    GEMM_DB_LOOP(pattB, seqWT, S_LEN, S_LEN, bm, bn, 0)

    // epilogue: tanh fusion
    int q4 = (lane >> 4) * 4;
#pragma unroll
    for (int fn = 0; fn < 4; ++fn) {
        int col = bn + wc * 64 + fn * 16 + lr;
        float bh = b_head[col], btl = b_tail[col];
#pragma unroll
        for (int fm = 0; fm < 4; ++fm) {
#pragma unroll
            for (int r = 0; r < 4; ++r) {
                int row = bm + wr * 64 + fm * 16 + q4 + r;
                int ph = pair_h[row], pt = pair_t[row];
                float c = acc[fm][fn][r];
                float hv = tanhf(ehet[(long)ph * 2048 + col] + bh + c);
                float tv = tanhf(ehet[(long)pt * 2048 + 1024 + col] + btl + c);
                zs[(long)row * PHID + col] = __float2bfloat16(hv);
                zo[(long)row * PHID + col] = __float2bfloat16(tv);
            }
        }
    }
    // out = b_bil init (one writer per row: col-tile 0, wc==0, fn irrelevant, lr==0)
    if (bx == 0 && wc == 0 && lr == 0) {
        float bb = b_bil[0];
#pragma unroll
        for (int fm = 0; fm < 4; ++fm)
#pragma unroll
            for (int r = 0; r < 4; ++r)
                out[bm + wr * 64 + fm * 16 + q4 + r] = bb;
    }
}

// ---------------------------------------------------------------------------
// L4) fused bilinear (double-buffered): A=zo, Bt=W_bil row-major, dot vs zs
// ---------------------------------------------------------------------------
__launch_bounds__(256)
__global__ void gemm_bilinear_db(const __hip_bfloat16* __restrict__ A,
                                 const __hip_bfloat16* __restrict__ Bt,
                                 const __hip_bfloat16* __restrict__ zvec,
                                 float* __restrict__ out,
                                 int M, int N, int Kstride, int kLen)
{
    __shared__ short As[2][8][128][8];
    __shared__ short Bs[2][8][128][8];
    int tid = threadIdx.x;
    int lane = tid & 63, wid = tid >> 6;
    int wr = wid >> 1, wc = wid & 1;
    int bm = blockIdx.y * 128, bn = blockIdx.x * 128;
    int kBeg = blockIdx.z * kLen;
    f32x4 acc[4][4] = {};
    int kg = lane >> 4, lr = lane & 15;

    GEMM_DB_LOOP(A, Bt, Kstride, kLen, bm, bn, kBeg)

    gemm_epilogue<2>(acc, nullptr, zvec, out, M, N, bm, bn, blockIdx.z, wr, wc, lane);
}

// ---------------------------------------------------------------------------
// Launch
// ---------------------------------------------------------------------------
extern "C" void kernel_launch(void* const* d_in, const int* in_sizes, int n_in,
                              void* d_out, int out_size, void* d_ws, size_t ws_size,
                              hipStream_t stream)
{
    const float* seq        = (const float*)d_in[0];
    const float* attention  = (const float*)d_in[1];
    const int*   mention_idx= (const int*)  d_in[2];
    const int*   entity_ids = (const int*)  d_in[3];
    const int*   pair_h     = (const int*)  d_in[4];
    const int*   pair_t     = (const int*)  d_in[5];
    const float* W_head     = (const float*)d_in[6];
    const float* b_head     = (const float*)d_in[7];
    const float* W_tail     = (const float*)d_in[8];
    const float* b_tail     = (const float*)d_in[9];
    const float* W_ctx      = (const float*)d_in[10];
    const float* W_bil      = (const float*)d_in[11];
    const float* b_bil      = (const float*)d_in[12];
    float* out = (float*)d_out;

    // ---- workspace (MB offsets) ----
    char* w = (char*)d_ws;
    __hip_bfloat16* seqB  = (__hip_bfloat16*)(w + 0);           // [S][H]       4 MB
    __hip_bfloat16* WctxT = (__hip_bfloat16*)(w + (4l << 20));  // [PH][H]      2 MB
    __hip_bfloat16* WhtT  = (__hip_bfloat16*)(w + (6l << 20));  // [2PH][H]     4 MB
    __hip_bfloat16* WbilB = (__hip_bfloat16*)(w + (10l << 20)); // [PH][PH]     2 MB (row-major cast)
    __hip_bfloat16* embB  = (__hip_bfloat16*)(w + (12l << 20)); // [E][H]       0.5 MB
    __hip_bfloat16* eaB   = (__hip_bfloat16*)(w + (13l << 20)); // [E][16][S]   16 MB
    __hip_bfloat16* pattB = (__hip_bfloat16*)(w + (29l << 20)); // [P][S]       8 MB
    __hip_bfloat16* seqWT = (__hip_bfloat16*)(w + (37l << 20)); // [PH][S]      4 MB
    __hip_bfloat16* zsB   = (__hip_bfloat16*)(w + (41l << 20)); // [P][PH]      4 MB
    __hip_bfloat16* zoB   = (__hip_bfloat16*)(w + (45l << 20)); // [P][PH]      4 MB
    float* ehet  = (float*)(w + (49l << 20));                   // [E][2PH]     2 MB

    // ---- L1: prep (casts + transposes) + entity emb/att (low-LDS, high occ) ----
    prep_ent_kernel<<<8960, 256, 0, stream>>>(seq, attention, W_ctx, W_head, W_tail, W_bil,
                                              mention_idx, entity_ids,
                                              seqB, WctxT, WhtT, WhtT + (long)PHID * HID, WbilB,
                                              (uint2*)eaB, embB);

    // ---- L2: seqW GEMM + ehet GEMM (full-K, fp32 direct) + pair attention ----
    pair_seqw_ehet<<<2208, 256, 0, stream>>>(WctxT, seqB, seqWT, embB, WhtT, ehet,
                                             (const uint4*)eaB, pair_h, pair_t, (uint4*)pattB);

    // ---- L3: fused ctxp GEMM + tanh -> zs/zo (+ out=b_bil) ----
    gemm_fused_zszo<<<128, 256, 0, stream>>>(pattB, seqWT, ehet, b_head, b_tail,
                                             pair_h, pair_t, zsB, zoB, b_bil, out);

    // ---- L4: fused bilinear (dbuf, splitK=4) ----
    gemm_bilinear_db<<<dim3(8, 16, 4), 256, 0, stream>>>(zoB, WbilB, zsB, out,
                                                         NP, PHID, HID, HID / 4);
}

// Round 12
// 130.813 us; speedup vs baseline: 1.3506x; 1.3506x over previous
//
#include <hip/hip_runtime.h>
#include <hip/hip_bf16.h>
#include <math.h>
#include <stdint.h>

// Problem constants
#define S_LEN  2048
#define HID    1024
#define NHEADS 16
#define NE     256
#define NMEN   1024
#define NP     2048
#define PHID   1024

typedef __attribute__((ext_vector_type(8))) short bf16x8;
typedef __attribute__((ext_vector_type(4))) float f32x4;
typedef unsigned int uint;

// ---------------------------------------------------------------------------
// Helpers
// ---------------------------------------------------------------------------
__device__ inline void seg_bounds(const int* __restrict__ entity_ids, int e,
                                  int& start, int& end) {
    int lo = 0, hi = NMEN;
    while (lo < hi) { int mid = (lo + hi) >> 1; if (entity_ids[mid] < e) lo = mid + 1; else hi = mid; }
    start = lo;
    hi = NMEN;
    while (lo < hi) { int mid = (lo + hi) >> 1; if (entity_ids[mid] <= e) lo = mid + 1; else hi = mid; }
    end = lo;
}

__device__ __forceinline__ void load_lds16(const void* g, void* l) {
    __builtin_amdgcn_global_load_lds(
        (const __attribute__((address_space(1))) uint32_t*)g,
        (__attribute__((address_space(3))) uint32_t*)l,
        16, 0, 0);
}

__device__ __forceinline__ float bflo(uint u) { return __uint_as_float(u << 16); }
__device__ __forceinline__ float bfhi(uint u) { return __uint_as_float(u & 0xffff0000u); }
__device__ __forceinline__ uint pk2(float a, float b) {
    __hip_bfloat16 ha = __float2bfloat16(a), hb = __float2bfloat16(b);
    unsigned short ua = *(unsigned short*)&ha, ub = *(unsigned short*)&hb;
    return (uint)ua | ((uint)ub << 16);
}

// ---------------------------------------------------------------------------
// L1) Merged prep + entity kernel (low LDS, high occupancy), 8960 blocks:
//   [0,1024)      seq fp32 -> bf16 cast (row-major)
//   [1024,4096)   3 weight transposes (W_ctx, W_head, W_tail) -> bf16
//   [4096,4608)   W_bil fp32 -> bf16 cast (row-major)
//   [4608,8960)   entity: e = t&255, role = t>>8 (0..15: att head; 16: emb)
// ---------------------------------------------------------------------------
__global__ void prep_ent_kernel(const float* __restrict__ seq,
                                const float* __restrict__ attention,
                                const float* __restrict__ w0, const float* __restrict__ w1,
                                const float* __restrict__ w2, const float* __restrict__ wbil,
                                const int* __restrict__ mention_idx,
                                const int* __restrict__ entity_ids,
                                __hip_bfloat16* __restrict__ seqB,
                                __hip_bfloat16* __restrict__ o0, __hip_bfloat16* __restrict__ o1,
                                __hip_bfloat16* __restrict__ o2, __hip_bfloat16* __restrict__ obil,
                                uint2* __restrict__ eaB,
                                __hip_bfloat16* __restrict__ ent_emb)
{
    __shared__ float tbuf[32][33];
    __shared__ int sb[2];
    int id = blockIdx.x;
    if (id < 1024) {
        long i = (long)id * 256 + threadIdx.x;
        const float4* in4 = (const float4*)seq;
        float4 a = in4[2 * i], b = in4[2 * i + 1];
        uint4 o;
        o.x = pk2(a.x, a.y); o.y = pk2(a.z, a.w);
        o.z = pk2(b.x, b.y); o.w = pk2(b.z, b.w);
        ((uint4*)seqB)[i] = o;
        return;
    }
    if (id < 4096) {
        int t = id - 1024;
        int z = t >> 10;
        const float* in = (z == 0) ? w0 : (z == 1) ? w1 : w2;
        __hip_bfloat16* out = (z == 0) ? o0 : (z == 1) ? o1 : o2;
        int r0 = ((t >> 5) & 31) * 32, c0 = (t & 31) * 32;
        int j = threadIdx.x & 31, i0 = threadIdx.x >> 5;
        for (int i = i0; i < 32; i += 8)
            tbuf[i][j] = in[(long)(r0 + i) * 1024 + c0 + j];
        __syncthreads();
        for (int i = i0; i < 32; i += 8)
            out[(long)(c0 + i) * 1024 + r0 + j] = __float2bfloat16(tbuf[j][i]);
        return;
    }
    if (id < 4608) {
        long i = (long)(id - 4096) * 256 + threadIdx.x;
        const float4* in4 = (const float4*)wbil;
        float4 a = in4[2 * i], b = in4[2 * i + 1];
        uint4 o;
        o.x = pk2(a.x, a.y); o.y = pk2(a.z, a.w);
        o.z = pk2(b.x, b.y); o.w = pk2(b.z, b.w);
        ((uint4*)obil)[i] = o;
        return;
    }
    // entity work
    int t = id - 4608;
    int e = t & 255, role = t >> 8;
    if (threadIdx.x == 0) { int s, tt; seg_bounds(entity_ids, e, s, tt); sb[0] = s; sb[1] = tt; }
    __syncthreads();
    int start = sb[0], end = sb[1];

    if (role < 16) {
        const float4* att4 = (const float4*)attention;
        int h = role;
        float inv = 1.f / fmaxf((float)(end - start), 1.f);
        for (int s4 = threadIdx.x; s4 < S_LEN / 4; s4 += 256) {
            float ax = 0.f, ay = 0.f, az = 0.f, aw = 0.f;
            for (int i = start; i < end; ++i) {
                float4 v = att4[((long)h * S_LEN + mention_idx[i]) * (S_LEN / 4) + s4];
                ax += v.x; ay += v.y; az += v.z; aw += v.w;
            }
            uint2 o; o.x = pk2(ax * inv, ay * inv); o.y = pk2(az * inv, aw * inv);
            eaB[((long)e * NHEADS + h) * (S_LEN / 4) + s4] = o;
        }
    } else {
        const float4* seq4 = (const float4*)seq;
        int col4 = threadIdx.x;
        uint2 o;
        if (end <= start) {
            o.x = 0; o.y = 0;
            ((uint2*)ent_emb)[(long)e * 256 + col4] = o;
            return;
        }
        float mx = -INFINITY, my = -INFINITY, mz = -INFINITY, mw = -INFINITY;
        for (int i = start; i < end; ++i) {
            float4 v = seq4[(long)mention_idx[i] * 256 + col4];
            mx = fmaxf(mx, v.x); my = fmaxf(my, v.y); mz = fmaxf(mz, v.z); mw = fmaxf(mw, v.w);
        }
        float sx = 0.f, sy = 0.f, sz = 0.f, sw = 0.f;
        for (int i = start; i < end; ++i) {
            float4 v = seq4[(long)mention_idx[i] * 256 + col4];
            sx += expf(v.x - mx); sy += expf(v.y - my); sz += expf(v.z - mz); sw += expf(v.w - mw);
        }
        o.x = pk2(mx + logf(sx), my + logf(sy));
        o.y = pk2(mz + logf(sz), mw + logf(sw));
        ((uint2*)ent_emb)[(long)e * 256 + col4] = o;
    }
}

// ---------------------------------------------------------------------------
// Shared GEMM epilogue: 128x128 tile, 4 waves (2x2).
//    MODE 0: fp32 at slice bz (bz=0 => direct fp32)
//    MODE 1: bf16 direct
//    MODE 2: fused bilinear: atomicAdd(out+row, sum_col acc*bf16(zvec)[row][col])
//    MODE 3: bf16 partial at slice bz
// ---------------------------------------------------------------------------
template <int MODE>
__device__ __forceinline__ void gemm_epilogue(
    f32x4 (&acc)[4][4], void* __restrict__ Cout,
    const __hip_bfloat16* __restrict__ zvec, float* __restrict__ out,
    int M, int N, int bm, int bn, int bz, int wr, int wc, int lane)
{
    int lr = lane & 15;
    int q4 = (lane >> 4) * 4;
    if (MODE == 0) {
#pragma unroll
        for (int fm = 0; fm < 4; ++fm)
#pragma unroll
            for (int fn = 0; fn < 4; ++fn) {
                int row = bm + wr * 64 + fm * 16 + q4;
                int col = bn + wc * 64 + fn * 16 + lr;
#pragma unroll
                for (int r = 0; r < 4; ++r)
                    ((float*)Cout)[((long)bz * M + row + r) * N + col] = acc[fm][fn][r];
            }
    } else if (MODE == 1) {
#pragma unroll
        for (int fm = 0; fm < 4; ++fm)
#pragma unroll
            for (int fn = 0; fn < 4; ++fn) {
                int row = bm + wr * 64 + fm * 16 + q4;
                int col = bn + wc * 64 + fn * 16 + lr;
#pragma unroll
                for (int r = 0; r < 4; ++r)
                    ((__hip_bfloat16*)Cout)[(long)(row + r) * N + col] = __float2bfloat16(acc[fm][fn][r]);
            }
    } else if (MODE == 3) {
#pragma unroll
        for (int fm = 0; fm < 4; ++fm)
#pragma unroll
            for (int fn = 0; fn < 4; ++fn) {
                int row = bm + wr * 64 + fm * 16 + q4;
                int col = bn + wc * 64 + fn * 16 + lr;
#pragma unroll
                for (int r = 0; r < 4; ++r)
                    ((__hip_bfloat16*)Cout)[((long)bz * M + row + r) * N + col] = __float2bfloat16(acc[fm][fn][r]);
            }
    } else {
#pragma unroll
        for (int fm = 0; fm < 4; ++fm) {
#pragma unroll
            for (int r = 0; r < 4; ++r) {
                int row = bm + wr * 64 + fm * 16 + q4 + r;
                float v = 0.f;
#pragma unroll
                for (int fn = 0; fn < 4; ++fn) {
                    int col = bn + wc * 64 + fn * 16 + lr;
                    v += acc[fm][fn][r] * __bfloat162float(zvec[(long)row * N + col]);
                }
                v += __shfl_xor(v, 1, 64);
                v += __shfl_xor(v, 2, 64);
                v += __shfl_xor(v, 4, 64);
                v += __shfl_xor(v, 8, 64);
                if (lr == 0) atomicAdd(out + row, v);
            }
        }
    }
}

#define COMPUTE_TILE(AsB, BsB) { _Pragma("unroll") \
    for (int sub = 0; sub < 2; ++sub) { \
        bf16x8 af[4], bfr[4]; \
        _Pragma("unroll") for (int f = 0; f < 4; ++f) { \
            af[f]  = *(const bf16x8*)&AsB[sub * 4 + kg][wr * 64 + f * 16 + lr][0]; \
            bfr[f] = *(const bf16x8*)&BsB[sub * 4 + kg][wc * 64 + f * 16 + lr][0]; \
        } \
        _Pragma("unroll") for (int fm = 0; fm < 4; ++fm) \
        _Pragma("unroll") for (int fn = 0; fn < 4; ++fn) \
            acc[fm][fn] = __builtin_amdgcn_mfma_f32_16x16x32_bf16(af[fm], bfr[fn], acc[fm][fn], 0, 0, 0); \
    } }

// ---------------------------------------------------------------------------
// Single-buffer GEMM core (32 KB LDS)
// ---------------------------------------------------------------------------
template <int MODE>
__device__ __forceinline__ void gemm_core(
    const __hip_bfloat16* __restrict__ A,
    const __hip_bfloat16* __restrict__ Bt,
    void* __restrict__ Cout, const __hip_bfloat16* __restrict__ zvec, float* __restrict__ out,
    int M, int N, int Kstride, int kLen,
    int bx, int by, int bz,
    short (*As)[128][8], short (*Bs)[128][8])
{
    int tid = threadIdx.x;
    int lane = tid & 63, wid = tid >> 6;
    int wr = wid >> 1, wc = wid & 1;
    int bm = by * 128, bn = bx * 128;
    int kBeg = bz * kLen;

    const __hip_bfloat16* gsrc[8];
    void* ldst[8];
#pragma unroll
    for (int i = 0; i < 8; ++i) {
        int c = wid * 8 + i;
        int isA = (c < 16) ? 1 : 0;
        int cc = isA ? c : c - 16;
        int kg2 = cc >> 1, rh = cc & 1;
        gsrc[i] = (isA ? A + (long)(bm + rh * 64 + lane) * Kstride
                       : Bt + (long)(bn + rh * 64 + lane) * Kstride) + kBeg + kg2 * 8;
        ldst[i] = isA ? (void*)&As[kg2][rh * 64][0] : (void*)&Bs[kg2][rh * 64][0];
    }

    f32x4 acc[4][4] = {};
    int kg = lane >> 4, lr = lane & 15;

    for (int k0 = 0; k0 < kLen; k0 += 64) {
#pragma unroll
        for (int i = 0; i < 8; ++i)
            load_lds16(gsrc[i] + k0, ldst[i]);
        __syncthreads();
        COMPUTE_TILE(As, Bs);
        __syncthreads();
    }
    gemm_epilogue<MODE>(acc, Cout, zvec, out, M, N, bm, bn, bz, wr, wc, lane);
}

// ---------------------------------------------------------------------------
// Double-buffered prefetch GEMM core (64 KB LDS). kLen % 128 == 0.
// ---------------------------------------------------------------------------
template <int MODE>
__device__ __forceinline__ void gemm_core_db(
    const __hip_bfloat16* __restrict__ A,
    const __hip_bfloat16* __restrict__ Bt,
    void* __restrict__ Cout, const __hip_bfloat16* __restrict__ zvec, float* __restrict__ out,
    int M, int N, int Kstride, int kLen,
    int bx, int by, int bz,
    short (*As)[8][128][8], short (*Bs)[8][128][8])
{
    int tid = threadIdx.x;
    int lane = tid & 63, wid = tid >> 6;
    int wr = wid >> 1, wc = wid & 1;
    int bm = by * 128, bn = bx * 128;
    int kBeg = bz * kLen;

    const __hip_bfloat16* gsrc[8];
    void *ld0[8], *ld1[8];
#pragma unroll
    for (int i = 0; i < 8; ++i) {
        int c = wid * 8 + i;
        int isA = (c < 16) ? 1 : 0;
        int cc = isA ? c : c - 16;
        int kg2 = cc >> 1, rh = cc & 1;
        gsrc[i] = (isA ? A + (long)(bm + rh * 64 + lane) * Kstride
                       : Bt + (long)(bn + rh * 64 + lane) * Kstride) + kBeg + kg2 * 8;
        ld0[i] = isA ? (void*)&As[0][kg2][rh * 64][0] : (void*)&Bs[0][kg2][rh * 64][0];
        ld1[i] = isA ? (void*)&As[1][kg2][rh * 64][0] : (void*)&Bs[1][kg2][rh * 64][0];
    }

    f32x4 acc[4][4] = {};
    int kg = lane >> 4, lr = lane & 15;
    int nSteps = kLen >> 6;

#define STAGE_DB(t, ld) { _Pragma("unroll") \
    for (int i = 0; i < 8; ++i) load_lds16(gsrc[i] + (t) * 64, ld[i]); }

    STAGE_DB(0, ld0);
    __syncthreads();
    for (int step = 0; step < nSteps; step += 2) {
        STAGE_DB(step + 1, ld1);
        COMPUTE_TILE(As[0], Bs[0]);
        __syncthreads();
        if (step + 2 < nSteps) STAGE_DB(step + 2, ld0);
        COMPUTE_TILE(As[1], Bs[1]);
        __syncthreads();
    }
#undef STAGE_DB
    gemm_epilogue<MODE>(acc, Cout, zvec, out, M, N, bm, bn, bz, wr, wc, lane);
}

// ---------------------------------------------------------------------------
// L2) Merged: seqW GEMM (128 blocks, MODE 1) + ehet GEMM (32 blocks, full-K,
//     fp32 direct) + pair attention (2048 blocks). Grid 2208.
// ---------------------------------------------------------------------------
__launch_bounds__(256)
__global__ void pair_seqw_ehet(const __hip_bfloat16* __restrict__ WctxT,
                               const __hip_bfloat16* __restrict__ seqB,
                               __hip_bfloat16* __restrict__ seqWT,
                               const __hip_bfloat16* __restrict__ embB,
                               const __hip_bfloat16* __restrict__ WhtT,
                               float* __restrict__ ehet,
                               const uint4* __restrict__ ea,
                               const int* __restrict__ pair_h,
                               const int* __restrict__ pair_t,
                               uint4* __restrict__ patt)
{
    __shared__ short As[8][128][8];
    __shared__ short Bs[8][128][8];
    int id = blockIdx.x;
    if (id < 128) {
        // seqWT[j][s] = (seq@W_ctx)[s][j]: A=WctxT, Bt=seqB; M=1024,N=2048,K=1024
        gemm_core<1>(WctxT, seqB, seqWT, nullptr, nullptr,
                     PHID, S_LEN, HID, HID, id & 15, id >> 4, 0, As, Bs);
        return;
    }
    if (id < 160) {
        // ehet = ent_emb @ [W_head|W_tail]: M=256,N=2048,K=1024 full-K, fp32 direct
        int u = id - 128;
        gemm_core<0>(embB, WhtT, ehet, nullptr, nullptr,
                     NE, 2 * PHID, HID, HID, u & 15, u >> 4, 0, As, Bs);
        return;
    }
    // pair attention
    __shared__ float wsum[4];
    int p = id - 160;
    long bh = (long)pair_h[p] * NHEADS * (S_LEN / 8);
    long bt = (long)pair_t[p] * NHEADS * (S_LEN / 8);
    int s8 = threadIdx.x;
    float a0 = 0, a1 = 0, a2 = 0, a3 = 0, a4 = 0, a5 = 0, a6 = 0, a7 = 0;
#pragma unroll
    for (int h = 0; h < NHEADS; ++h) {
        uint4 xa = ea[bh + h * (S_LEN / 8) + s8];
        uint4 xb = ea[bt + h * (S_LEN / 8) + s8];
        a0 += bflo(xa.x) * bflo(xb.x); a1 += bfhi(xa.x) * bfhi(xb.x);
        a2 += bflo(xa.y) * bflo(xb.y); a3 += bfhi(xa.y) * bfhi(xb.y);
        a4 += bflo(xa.z) * bflo(xb.z); a5 += bfhi(xa.z) * bfhi(xb.z);
        a6 += bflo(xa.w) * bflo(xb.w); a7 += bfhi(xa.w) * bfhi(xb.w);
    }
    float psum = a0 + a1 + a2 + a3 + a4 + a5 + a6 + a7;
#pragma unroll
    for (int off = 32; off > 0; off >>= 1)
        psum += __shfl_down(psum, off, 64);
    int lane = threadIdx.x & 63, wid = threadIdx.x >> 6;
    if (lane == 0) wsum[wid] = psum;
    __syncthreads();
    float inv = 1.f / (wsum[0] + wsum[1] + wsum[2] + wsum[3] + 1e-6f);
    uint4 o;
    o.x = pk2(a0 * inv, a1 * inv); o.y = pk2(a2 * inv, a3 * inv);
    o.z = pk2(a4 * inv, a5 * inv); o.w = pk2(a6 * inv, a7 * inv);
    patt[(long)p * (S_LEN / 8) + s8] = o;
}

// ---------------------------------------------------------------------------
// L3) ctxp GEMM, 512 blocks, bf16 partials (splitK=4), XCD-chunked, dbuf
// ---------------------------------------------------------------------------
__launch_bounds__(256)
__global__ void gemm_ctxp(const __hip_bfloat16* __restrict__ pattB,
                          const __hip_bfloat16* __restrict__ seqWT,
                          __hip_bfloat16* __restrict__ ctxpB)
{
    __shared__ short As[2][8][128][8];
    __shared__ short Bs[2][8][128][8];
    int id = blockIdx.x;
    // XCD-chunked bijection: all 64 blocks of an XCD share bx (same B tile)
    int f = (id & 7) * 64 + (id >> 3);
    int bx = f >> 6, inner = f & 63;
    int by = inner & 15, bz = inner >> 4;
    gemm_core_db<3>(pattB, seqWT, ctxpB, nullptr, nullptr,
                    NP, PHID, S_LEN, S_LEN / 4, bx, by, bz, As, Bs);
}

// ---------------------------------------------------------------------------
// L4) zs/zo (+ out = b_bil init): folds ctxp 4-slice bf16 sum; 4 j per thread
// ---------------------------------------------------------------------------
__global__ void zs_zo_kernel(const __hip_bfloat16* __restrict__ ctxpB,  // [4][P][PH] bf16
                             const float* __restrict__ ehet,            // [E][2PH] fp32
                             const float* __restrict__ b_head,
                             const float* __restrict__ b_tail,
                             const int* __restrict__ pair_h,
                             const int* __restrict__ pair_t,
                             __hip_bfloat16* __restrict__ zs,
                             __hip_bfloat16* __restrict__ zo,
                             const float* __restrict__ b_bil, float* __restrict__ out)
{
    long base = ((long)blockIdx.x * 256 + threadIdx.x) * 4;
    if (base < NP) {
        float bb = b_bil[0];
#pragma unroll
        for (int i = 0; i < 4; ++i) out[base + i] = bb;
    }
    int p = (int)(base >> 10);
    int j = (int)(base & (PHID - 1));
    const long n = (long)NP * PHID;
    float c0 = 0.f, c1 = 0.f, c2 = 0.f, c3 = 0.f;
#pragma unroll
    for (int s = 0; s < 4; ++s) {
        uint2 u = *(const uint2*)&ctxpB[s * n + base];
        c0 += bflo(u.x); c1 += bfhi(u.x); c2 += bflo(u.y); c3 += bfhi(u.y);
    }
    float4 eh = *(const float4*)&ehet[(long)pair_h[p] * 2048 + j];
    float4 et = *(const float4*)&ehet[(long)pair_t[p] * 2048 + 1024 + j];
    float4 bh = *(const float4*)&b_head[j];
    float4 bt = *(const float4*)&b_tail[j];
    float h0 = tanhf(eh.x + bh.x + c0), h1 = tanhf(eh.y + bh.y + c1);
    float h2 = tanhf(eh.z + bh.z + c2), h3 = tanhf(eh.w + bh.w + c3);
    float t0 = tanhf(et.x + bt.x + c0), t1 = tanhf(et.y + bt.y + c1);
    float t2 = tanhf(et.z + bt.z + c2), t3 = tanhf(et.w + bt.w + c3);
    uint2 ozs; ozs.x = pk2(h0, h1); ozs.y = pk2(h2, h3);
    uint2 ozo; ozo.x = pk2(t0, t1); ozo.y = pk2(t2, t3);
    *(uint2*)&zs[base] = ozs;
    *(uint2*)&zo[base] = ozo;
}

// ---------------------------------------------------------------------------
// L5) fused bilinear (double-buffered): A=zo, Bt=W_bil row-major, dot vs zs
// ---------------------------------------------------------------------------
template <int MODE>
__launch_bounds__(256)
__global__ void gemm_single_db(const __hip_bfloat16* __restrict__ A,
                               const __hip_bfloat16* __restrict__ Bt,
                               void* __restrict__ Cout,
                               const __hip_bfloat16* __restrict__ zvec,
                               float* __restrict__ out,
                               int M, int N, int Kstride, int kLen)
{
    __shared__ short As[2][8][128][8];
    __shared__ short Bs[2][8][128][8];
    gemm_core_db<MODE>(A, Bt, Cout, zvec, out, M, N, Kstride, kLen,
                       blockIdx.x, blockIdx.y, blockIdx.z, As, Bs);
}

// ---------------------------------------------------------------------------
// Launch
// ---------------------------------------------------------------------------
extern "C" void kernel_launch(void* const* d_in, const int* in_sizes, int n_in,
                              void* d_out, int out_size, void* d_ws, size_t ws_size,
                              hipStream_t stream)
{
    const float* seq        = (const float*)d_in[0];
    const float* attention  = (const float*)d_in[1];
    const int*   mention_idx= (const int*)  d_in[2];
    const int*   entity_ids = (const int*)  d_in[3];
    const int*   pair_h     = (const int*)  d_in[4];
    const int*   pair_t     = (const int*)  d_in[5];
    const float* W_head     = (const float*)d_in[6];
    const float* b_head     = (const float*)d_in[7];
    const float* W_tail     = (const float*)d_in[8];
    const float* b_tail     = (const float*)d_in[9];
    const float* W_ctx      = (const float*)d_in[10];
    const float* W_bil      = (const float*)d_in[11];
    const float* b_bil      = (const float*)d_in[12];
    float* out = (float*)d_out;

    // ---- workspace (MB offsets) ----
    char* w = (char*)d_ws;
    __hip_bfloat16* seqB  = (__hip_bfloat16*)(w + 0);           // [S][H]       4 MB
    __hip_bfloat16* WctxT = (__hip_bfloat16*)(w + (4l << 20));  // [PH][H]      2 MB
    __hip_bfloat16* WhtT  = (__hip_bfloat16*)(w + (6l << 20));  // [2PH][H]     4 MB
    __hip_bfloat16* WbilB = (__hip_bfloat16*)(w + (10l << 20)); // [PH][PH]     2 MB (row-major cast)
    __hip_bfloat16* embB  = (__hip_bfloat16*)(w + (12l << 20)); // [E][H]       0.5 MB
    __hip_bfloat16* eaB   = (__hip_bfloat16*)(w + (13l << 20)); // [E][16][S]   16 MB
    __hip_bfloat16* pattB = (__hip_bfloat16*)(w + (29l << 20)); // [P][S]       8 MB
    __hip_bfloat16* seqWT = (__hip_bfloat16*)(w + (37l << 20)); // [PH][S]      4 MB
    __hip_bfloat16* zsB   = (__hip_bfloat16*)(w + (41l << 20)); // [P][PH]      4 MB
    __hip_bfloat16* zoB   = (__hip_bfloat16*)(w + (45l << 20)); // [P][PH]      4 MB
    __hip_bfloat16* ctxpB = (__hip_bfloat16*)(w + (49l << 20)); // [4][P][PH]   16 MB
    float* ehet  = (float*)(w + (65l << 20));                   // [E][2PH]     2 MB

    // ---- L1: prep (casts + transposes) + entity emb/att ----
    prep_ent_kernel<<<8960, 256, 0, stream>>>(seq, attention, W_ctx, W_head, W_tail, W_bil,
                                              mention_idx, entity_ids,
                                              seqB, WctxT, WhtT, WhtT + (long)PHID * HID, WbilB,
                                              (uint2*)eaB, embB);

    // ---- L2: seqW GEMM + ehet GEMM (full-K, fp32 direct) + pair attention ----
    pair_seqw_ehet<<<2208, 256, 0, stream>>>(WctxT, seqB, seqWT, embB, WhtT, ehet,
                                             (const uint4*)eaB, pair_h, pair_t, (uint4*)pattB);

    // ---- L3: ctxp bf16 partials (splitK=4, dbuf, XCD-chunked) ----
    gemm_ctxp<<<512, 256, 0, stream>>>(pattB, seqWT, ctxpB);

    // ---- L4: zs/zo (bf16) + out=b_bil ----
    zs_zo_kernel<<<2048, 256, 0, stream>>>(ctxpB, ehet, b_head, b_tail, pair_h, pair_t,
                                           zsB, zoB, b_bil, out);

    // ---- L5: fused bilinear (dbuf, splitK=4) ----
    gemm_single_db<2><<<dim3(8, 16, 4), 256, 0, stream>>>(zoB, WbilB, nullptr, zsB, out,
                                                          NP, PHID, HID, HID / 4);
}